// Round 11
// baseline (89.307 us; speedup 1.0000x reference)
//
#include <hip/hip_runtime.h>
#include <hip/hip_bf16.h>

#define DIMV 512
#define HDV  64
#define VSTR 524                          // shorts per Vt row (1048 B): vf reads conflict-free
#define KRING_B 32768                     // 2 slots x 16 KB, frag-ordered K chunks (128 keys)
#define VT_BASE KRING_B
#define SMEM_B (VT_BASE + 64 * VSTR * 2)  // 99,840 B

typedef __bf16 bf16x8_t __attribute__((ext_vector_type(8)));
typedef float f32x4_t __attribute__((ext_vector_type(4)));

union Frag { bf16x8_t v; unsigned short u[8]; unsigned int w[4]; uint2 d[2]; uint4 q; };

static __device__ __forceinline__ unsigned short f2bf(float f) {
  return __builtin_bit_cast(unsigned short, (__bf16)f);
}
static __device__ __forceinline__ float bf2f(unsigned int h) {
  return __builtin_bit_cast(float, h << 16);
}
static __device__ __forceinline__ uint2 pack4(const float4 f) {
  uint2 r;
  r.x = (unsigned)f2bf(f.x) | ((unsigned)f2bf(f.y) << 16);
  r.y = (unsigned)f2bf(f.z) | ((unsigned)f2bf(f.w) << 16);
  return r;
}

// LDS-visibility-only barrier: vmcnt NOT drained (carrier loads stay in flight).
#define BARRIER_NODRAIN() asm volatile("s_waitcnt lgkmcnt(0)\n\ts_barrier" ::: "memory")

__global__ __launch_bounds__(1024, 4)
void lepe_attn_kernel(const float* __restrict__ qkv,
                      const float* __restrict__ lw,
                      const float* __restrict__ lb,
                      float* __restrict__ out)
{
  __shared__ __align__(16) unsigned char smem[SMEM_B];

  const int head = blockIdx.x & 7;
  const int win  = blockIdx.x >> 3;
  const int bat  = win >> 3;
  const int nw   = win & 7;

  const int tid  = threadIdx.x;
  const int wave = tid >> 6, lane = tid & 63;
  const int l15  = lane & 15, g = lane >> 4;

  const float* qptr = qkv;
  const float* kptr = qkv + 16777216;
  const float* vptr = qkv + 33554432;
  const int rowbase = bat * 4096;

  auto grow = [&](int tok) -> int {
    return rowbase + ((tok >> 3) << 6) + (nw << 3) + (tok & 7);
  };

  // ---- staging mapping: token s_t (0..63 within group), channel quad s_c ----
  const int s_t = tid >> 4;
  const int s_c = (tid & 15) * 4;
  const size_t GSTRIDE = 262144;            // floats between 64-token groups
  const float* kg = kptr + (size_t)grow(s_t) * DIMV + head * HDV + s_c;
  const float* vg = vptr + (size_t)grow(s_t) * DIMV + head * HDV + s_c;

  // K fragment write byte within a 16 KB chunk slot (group gi adds 8192):
  // tile 4096 B = [ki 2][kc 2][lane 64][16 B]
  const int lr   = s_t & 31;
  const int kwb0 = (s_t >> 5) * 4096 + (lr >> 4) * 2048 + (s_c >> 5) * 1024
                 + ((lr & 15) + 16 * ((s_c >> 3) & 3)) * 16 + (s_c & 7) * 2;

  float4 ck0, ck1;   // K chunk carrier (8 VGPR)
  auto issueK = [&](int c) {
    ck0 = *(const float4*)(kg + (size_t)(2 * c) * GSTRIDE);
    ck1 = *(const float4*)(kg + (size_t)(2 * c + 1) * GSTRIDE);
  };
  auto writeK = [&](int c) {
    unsigned char* slot = smem + (c & 1) * 16384;
    *(uint2*)(slot + kwb0)        = pack4(ck0);
    *(uint2*)(slot + 8192 + kwb0) = pack4(ck1);
  };

  // ---- prologue: K chunk0 + all V + Q issued; convert; publish ----
  issueK(0);
  float4 vin[8];
  #pragma unroll
  for (int j = 0; j < 8; ++j) vin[j] = *(const float4*)(vg + (size_t)j * GSTRIDE);

  const float QSC = 0.1803368801f;          // 0.125 * log2(e): P = exp2(S)
  const int qbase = wave * 32;
  float4 qin[8];
  #pragma unroll
  for (int qi = 0; qi < 2; ++qi) {
    const float* qp = qptr + (size_t)grow(qbase + qi * 16 + l15) * DIMV + head * HDV;
    #pragma unroll
    for (int kc = 0; kc < 2; ++kc) {
      qin[qi * 4 + kc * 2 + 0] = *(const float4*)(qp + kc * 32 + 8 * g);
      qin[qi * 4 + kc * 2 + 1] = *(const float4*)(qp + kc * 32 + 8 * g + 4);
    }
  }

  writeK(0);
  // V^T resident: element (d, t) at VT_BASE + d*1048 + 2t
  #pragma unroll
  for (int j = 0; j < 8; ++j) {
    const int t = j * 64 + s_t;
    float fv[4] = {vin[j].x, vin[j].y, vin[j].z, vin[j].w};
    #pragma unroll
    for (int i = 0; i < 4; ++i)
      *(unsigned short*)(smem + VT_BASE + (s_c + i) * 1048 + 2 * t) = f2bf(fv[i]);
  }

  Frag qf[2][2];
  #pragma unroll
  for (int qi = 0; qi < 2; ++qi)
    #pragma unroll
    for (int kc = 0; kc < 2; ++kc) {
      const float4 f0 = qin[qi * 4 + kc * 2 + 0];
      const float4 f1 = qin[qi * 4 + kc * 2 + 1];
      qf[qi][kc].u[0] = f2bf(f0.x * QSC); qf[qi][kc].u[1] = f2bf(f0.y * QSC);
      qf[qi][kc].u[2] = f2bf(f0.z * QSC); qf[qi][kc].u[3] = f2bf(f0.w * QSC);
      qf[qi][kc].u[4] = f2bf(f1.x * QSC); qf[qi][kc].u[5] = f2bf(f1.y * QSC);
      qf[qi][kc].u[6] = f2bf(f1.z * QSC); qf[qi][kc].u[7] = f2bf(f1.w * QSC);
    }

  __syncthreads();

  const f32x4_t zero4 = {0.f, 0.f, 0.f, 0.f};
  f32x4_t ot[4][2];
  #pragma unroll
  for (int di = 0; di < 4; ++di)
    #pragma unroll
    for (int qi = 0; qi < 2; ++qi) ot[di][qi] = zero4;
  float lsum[2] = {0.f, 0.f};

  // ---- explicit tile double-buffer (ping-pong): forces ILP across tiles ----
  Frag kf[2][2][2];   // [buf][ki][kc]
  Frag vf[2][4];      // [buf][di]

#define LOADF(B, CC, T4, KT) do {                                             \
    const unsigned char* kb_ = smem + ((CC) & 1) * 16384 + (T4) * 4096        \
                               + lane * 16;                                   \
    kf[B][0][0].q = *(const uint4*)(kb_);                                     \
    kf[B][0][1].q = *(const uint4*)(kb_ + 1024);                              \
    kf[B][1][0].q = *(const uint4*)(kb_ + 2048);                              \
    kf[B][1][1].q = *(const uint4*)(kb_ + 3072);                              \
    _Pragma("unroll")                                                         \
    for (int di_ = 0; di_ < 4; ++di_) {                                       \
      const unsigned char* vr_ = smem + VT_BASE + (di_ * 16 + l15) * 1048     \
                                 + (KT) * 64 + 8 * g;                         \
      vf[B][di_].d[0] = *(const uint2*)(vr_);                                 \
      vf[B][di_].d[1] = *(const uint2*)(vr_ + 32);                            \
    }                                                                         \
  } while (0)

#define COMPUTE(B) do {                                                       \
    f32x4_t st[2][2];                                                         \
    _Pragma("unroll")                                                         \
    for (int ki_ = 0; ki_ < 2; ++ki_)                                         \
      _Pragma("unroll")                                                       \
      for (int qi_ = 0; qi_ < 2; ++qi_) st[ki_][qi_] = zero4;                 \
    __builtin_amdgcn_s_setprio(1);                                            \
    _Pragma("unroll")                                                         \
    for (int kc_ = 0; kc_ < 2; ++kc_)                                         \
      _Pragma("unroll")                                                       \
      for (int ki_ = 0; ki_ < 2; ++ki_)                                       \
        _Pragma("unroll")                                                     \
        for (int qi_ = 0; qi_ < 2; ++qi_)                                     \
          st[ki_][qi_] = __builtin_amdgcn_mfma_f32_16x16x32_bf16(             \
              kf[B][ki_][kc_].v, qf[qi_][kc_].v, st[ki_][qi_], 0, 0, 0);      \
    __builtin_amdgcn_s_setprio(0);                                            \
    _Pragma("unroll")                                                         \
    for (int ki_ = 0; ki_ < 2; ++ki_)                                         \
      _Pragma("unroll")                                                       \
      for (int qi_ = 0; qi_ < 2; ++qi_) {                                     \
        f32x4_t s_ = st[ki_][qi_];                                            \
        _Pragma("unroll")                                                     \
        for (int r_ = 0; r_ < 4; ++r_) {                                      \
          float p_ = __builtin_amdgcn_exp2f(s_[r_]);                          \
          s_[r_] = p_;                                                        \
          lsum[qi_] += p_;                                                    \
        }                                                                     \
        st[ki_][qi_] = s_;                                                    \
      }                                                                       \
    __builtin_amdgcn_s_setprio(1);                                            \
    _Pragma("unroll")                                                         \
    for (int qi_ = 0; qi_ < 2; ++qi_) {                                       \
      Frag pb_;                                                               \
      _Pragma("unroll")                                                       \
      for (int r_ = 0; r_ < 4; ++r_) {                                        \
        pb_.u[r_]     = f2bf(st[0][qi_][r_]);                                 \
        pb_.u[4 + r_] = f2bf(st[1][qi_][r_]);                                 \
      }                                                                       \
      _Pragma("unroll")                                                       \
      for (int di_ = 0; di_ < 4; ++di_)                                       \
        ot[di_][qi_] = __builtin_amdgcn_mfma_f32_16x16x32_bf16(               \
            vf[B][di_].v, pb_.v, ot[di_][qi_], 0, 0, 0);                      \
    }                                                                         \
    __builtin_amdgcn_s_setprio(0);                                            \
  } while (0)

  LOADF(0, 0, 0, 0);

  // ---- main loop: 4 chunks x 4 tiles of 32 keys; K streamed 1-chunk-ahead,
  //      fragments prefetched 1-tile-ahead ----
  #pragma unroll
  for (int c = 0; c < 4; ++c) {
    if (c < 3) issueK(c + 1);

    #pragma unroll
    for (int t4 = 0; t4 < 4; ++t4) {
      const int kt = c * 4 + t4;
      if (t4 == 0) { LOADF(1, c, 1, kt + 1); COMPUTE(0); }
      else if (t4 == 1) { LOADF(0, c, 2, kt + 1); COMPUTE(1); }
      else if (t4 == 2) { LOADF(1, c, 3, kt + 1); COMPUTE(0); }
      else { COMPUTE(1); }
    }

    if (c < 3) {
      writeK(c + 1);
      BARRIER_NODRAIN();
      LOADF(0, c + 1, 0, (c + 1) * 4);
    }
  }

  // ---- softmax denominators ----
  float rl[2];
  #pragma unroll
  for (int qi = 0; qi < 2; ++qi) {
    float s = lsum[qi];
    s += __shfl_xor(s, 16, 64);
    s += __shfl_xor(s, 32, 64);
    rl[qi] = 1.0f / s;
  }

  // ---- LePE conv from Vt LDS (lane = channel), wave rows wave*4..+3 ----
  float lout[32];
  {
    float wgt[9];
    const float* wp = lw + (size_t)(head * HDV + lane) * 9;
    #pragma unroll
    for (int i = 0; i < 9; ++i) wgt[i] = wp[i];
    const float bias = lb[head * HDV + lane];
    const int yb = wave * 4;
    const unsigned char* vrow = smem + VT_BASE + lane * 1048;

    float rm[8], rc[8], rp2[8];
    auto loadrow = [&](int y, float* dst) {
      if ((unsigned)y < 64u) {
        uint4 a = *(const uint4*)(vrow + y * 16);
        dst[0] = bf2f(a.x & 0xffffu); dst[1] = bf2f(a.x >> 16);
        dst[2] = bf2f(a.y & 0xffffu); dst[3] = bf2f(a.y >> 16);
        dst[4] = bf2f(a.z & 0xffffu); dst[5] = bf2f(a.z >> 16);
        dst[6] = bf2f(a.w & 0xffffu); dst[7] = bf2f(a.w >> 16);
      } else {
        #pragma unroll
        for (int x = 0; x < 8; ++x) dst[x] = 0.f;
      }
    };
    loadrow(yb - 1, rm);
    loadrow(yb, rc);
    #pragma unroll
    for (int yy = 0; yy < 4; ++yy) {
      loadrow(yb + yy + 1, rp2);
      #pragma unroll
      for (int x = 0; x < 8; ++x) {
        float acc = bias;
        if (x > 0) acc += rm[x-1]*wgt[0] + rc[x-1]*wgt[3] + rp2[x-1]*wgt[6];
        acc += rm[x]*wgt[1] + rc[x]*wgt[4] + rp2[x]*wgt[7];
        if (x < 7) acc += rm[x+1]*wgt[2] + rc[x+1]*wgt[5] + rp2[x+1]*wgt[8];
        lout[yy * 8 + x] = acc;
      }
      #pragma unroll
      for (int x = 0; x < 8; ++x) { rm[x] = rc[x]; rc[x] = rp2[x]; }
    }
  }

  BARRIER_NODRAIN();   // all PV + LePE reads of K/Vt done; LDS reusable

  unsigned char* bp = smem + wave * 4352;   // [32 tok][68 ch] bf16 per wave
  #pragma unroll
  for (int t = 0; t < 32; ++t)
    *(unsigned short*)(bp + t * 136 + 2 * lane) = f2bf(lout[t]);
  BARRIER_NODRAIN();

  // ---- normalize, add LePE, store ----
  #pragma unroll
  for (int qi = 0; qi < 2; ++qi) {
    const float rlq = rl[qi];
    const int tl = qi * 16 + l15;
    float* op = out + (size_t)grow(qbase + tl) * DIMV + head * HDV;
    #pragma unroll
    for (int di = 0; di < 4; ++di) {
      uint2 lv = *(const uint2*)(bp + tl * 136 + di * 32 + 8 * g);
      float4 o;
      o.x = ot[di][qi][0] * rlq + bf2f(lv.x & 0xffffu);
      o.y = ot[di][qi][1] * rlq + bf2f(lv.x >> 16);
      o.z = ot[di][qi][2] * rlq + bf2f(lv.y & 0xffffu);
      o.w = ot[di][qi][3] * rlq + bf2f(lv.y >> 16);
      *(float4*)(op + di * 16 + 4 * g) = o;
    }
  }
#undef LOADF
#undef COMPUTE
}

extern "C" void kernel_launch(void* const* d_in, const int* in_sizes, int n_in,
                              void* d_out, int out_size, void* d_ws, size_t ws_size,
                              hipStream_t stream) {
  const float* qkv = (const float*)d_in[0];
  const float* lw  = (const float*)d_in[1];
  const float* lb  = (const float*)d_in[2];
  float* out = (float*)d_out;
  (void)in_sizes; (void)n_in; (void)out_size; (void)d_ws; (void)ws_size;

  dim3 grid(512);    // 64 win x 8 heads
  dim3 block(1024);  // 16 waves x 32 queries
  hipLaunchKernelGGL(lepe_attn_kernel, grid, block, 0, stream, qkv, lw, lb, out);
}

// Round 12
// 89.266 us; speedup vs baseline: 1.0005x; 1.0005x over previous
//
#include <hip/hip_runtime.h>
#include <hip/hip_bf16.h>

#define DIMV 512
#define HDV  64
#define VSTR 524                          // shorts per Vt row (1048 B): vf reads conflict-free
#define KRING_B 32768                     // 2 slots x 16 KB, frag-ordered K chunks (128 keys)
#define VT_BASE KRING_B
#define SMEM_B (VT_BASE + 64 * VSTR * 2)  // 99,840 B

typedef __bf16 bf16x8_t __attribute__((ext_vector_type(8)));
typedef float f32x4_t __attribute__((ext_vector_type(4)));

union Frag { bf16x8_t v; unsigned short u[8]; unsigned int w[4]; uint2 d[2]; uint4 q; };

static __device__ __forceinline__ unsigned short f2bf(float f) {
  return __builtin_bit_cast(unsigned short, (__bf16)f);
}
static __device__ __forceinline__ float bf2f(unsigned int h) {
  return __builtin_bit_cast(float, h << 16);
}
static __device__ __forceinline__ uint2 pack4(const float4 f) {
  uint2 r;
  r.x = (unsigned)f2bf(f.x) | ((unsigned)f2bf(f.y) << 16);
  r.y = (unsigned)f2bf(f.z) | ((unsigned)f2bf(f.w) << 16);
  return r;
}

// LDS-visibility-only barrier: vmcnt NOT drained (carrier loads stay in flight).
#define BARRIER_NODRAIN() asm volatile("s_waitcnt lgkmcnt(0)\n\ts_barrier" ::: "memory")

// waves_per_eu(4,4): LDS (99.8 KB) caps us at 1 block/CU = 4 waves/EU anyway.
// Pinning min=max=4 gives the allocator the full 128-VGPR budget and forbids
// spilling in pursuit of an unreachable 8-waves/EU occupancy (R7-R11 disease).
__global__ __launch_bounds__(1024) __attribute__((amdgpu_waves_per_eu(4, 4)))
void lepe_attn_kernel(const float* __restrict__ qkv,
                      const float* __restrict__ lw,
                      const float* __restrict__ lb,
                      float* __restrict__ out)
{
  __shared__ __align__(16) unsigned char smem[SMEM_B];

  const int head = blockIdx.x & 7;
  const int win  = blockIdx.x >> 3;
  const int bat  = win >> 3;
  const int nw   = win & 7;

  const int tid  = threadIdx.x;
  const int wave = tid >> 6, lane = tid & 63;
  const int l15  = lane & 15, g = lane >> 4;

  const float* qptr = qkv;
  const float* kptr = qkv + 16777216;
  const float* vptr = qkv + 33554432;
  const int rowbase = bat * 4096;

  auto grow = [&](int tok) -> int {
    return rowbase + ((tok >> 3) << 6) + (nw << 3) + (tok & 7);
  };

  // ---- staging mapping: token s_t (0..63 within group), channel quad s_c ----
  const int s_t = tid >> 4;
  const int s_c = (tid & 15) * 4;
  const size_t GSTRIDE = 262144;            // floats between 64-token groups
  const float* kg = kptr + (size_t)grow(s_t) * DIMV + head * HDV + s_c;
  const float* vg = vptr + (size_t)grow(s_t) * DIMV + head * HDV + s_c;

  // K fragment write byte within a 16 KB chunk slot (group gi adds 8192):
  // tile 4096 B = [ki 2][kc 2][lane 64][16 B]
  const int lr   = s_t & 31;
  const int kwb0 = (s_t >> 5) * 4096 + (lr >> 4) * 2048 + (s_c >> 5) * 1024
                 + ((lr & 15) + 16 * ((s_c >> 3) & 3)) * 16 + (s_c & 7) * 2;

  float4 ck0, ck1;   // K chunk carrier (8 VGPR)
  auto issueK = [&](int c) {
    ck0 = *(const float4*)(kg + (size_t)(2 * c) * GSTRIDE);
    ck1 = *(const float4*)(kg + (size_t)(2 * c + 1) * GSTRIDE);
  };
  auto writeK = [&](int c) {
    unsigned char* slot = smem + (c & 1) * 16384;
    *(uint2*)(slot + kwb0)        = pack4(ck0);
    *(uint2*)(slot + 8192 + kwb0) = pack4(ck1);
  };

  // ---- prologue: K chunk0 + all V + Q issued; convert; publish ----
  issueK(0);
  float4 vin[8];
  #pragma unroll
  for (int j = 0; j < 8; ++j) vin[j] = *(const float4*)(vg + (size_t)j * GSTRIDE);

  const float QSC = 0.1803368801f;          // 0.125 * log2(e): P = exp2(S)
  const int qbase = wave * 32;
  float4 qin[8];
  #pragma unroll
  for (int qi = 0; qi < 2; ++qi) {
    const float* qp = qptr + (size_t)grow(qbase + qi * 16 + l15) * DIMV + head * HDV;
    #pragma unroll
    for (int kc = 0; kc < 2; ++kc) {
      qin[qi * 4 + kc * 2 + 0] = *(const float4*)(qp + kc * 32 + 8 * g);
      qin[qi * 4 + kc * 2 + 1] = *(const float4*)(qp + kc * 32 + 8 * g + 4);
    }
  }

  writeK(0);
  // V^T resident: element (d, t) at VT_BASE + d*1048 + 2t
  #pragma unroll
  for (int j = 0; j < 8; ++j) {
    const int t = j * 64 + s_t;
    float fv[4] = {vin[j].x, vin[j].y, vin[j].z, vin[j].w};
    #pragma unroll
    for (int i = 0; i < 4; ++i)
      *(unsigned short*)(smem + VT_BASE + (s_c + i) * 1048 + 2 * t) = f2bf(fv[i]);
  }

  Frag qf[2][2];
  #pragma unroll
  for (int qi = 0; qi < 2; ++qi)
    #pragma unroll
    for (int kc = 0; kc < 2; ++kc) {
      const float4 f0 = qin[qi * 4 + kc * 2 + 0];
      const float4 f1 = qin[qi * 4 + kc * 2 + 1];
      qf[qi][kc].u[0] = f2bf(f0.x * QSC); qf[qi][kc].u[1] = f2bf(f0.y * QSC);
      qf[qi][kc].u[2] = f2bf(f0.z * QSC); qf[qi][kc].u[3] = f2bf(f0.w * QSC);
      qf[qi][kc].u[4] = f2bf(f1.x * QSC); qf[qi][kc].u[5] = f2bf(f1.y * QSC);
      qf[qi][kc].u[6] = f2bf(f1.z * QSC); qf[qi][kc].u[7] = f2bf(f1.w * QSC);
    }

  __syncthreads();

  const f32x4_t zero4 = {0.f, 0.f, 0.f, 0.f};
  f32x4_t ot[4][2];
  #pragma unroll
  for (int di = 0; di < 4; ++di)
    #pragma unroll
    for (int qi = 0; qi < 2; ++qi) ot[di][qi] = zero4;
  float lsum[2] = {0.f, 0.f};

  // ---- explicit tile double-buffer (ping-pong): forces ILP across tiles ----
  Frag kf[2][2][2];   // [buf][ki][kc]
  Frag vf[2][4];      // [buf][di]

#define LOADF(B, CC, T4, KT) do {                                             \
    const unsigned char* kb_ = smem + ((CC) & 1) * 16384 + (T4) * 4096        \
                               + lane * 16;                                   \
    kf[B][0][0].q = *(const uint4*)(kb_);                                     \
    kf[B][0][1].q = *(const uint4*)(kb_ + 1024);                              \
    kf[B][1][0].q = *(const uint4*)(kb_ + 2048);                              \
    kf[B][1][1].q = *(const uint4*)(kb_ + 3072);                              \
    _Pragma("unroll")                                                         \
    for (int di_ = 0; di_ < 4; ++di_) {                                       \
      const unsigned char* vr_ = smem + VT_BASE + (di_ * 16 + l15) * 1048     \
                                 + (KT) * 64 + 8 * g;                         \
      vf[B][di_].d[0] = *(const uint2*)(vr_);                                 \
      vf[B][di_].d[1] = *(const uint2*)(vr_ + 32);                            \
    }                                                                         \
  } while (0)

#define COMPUTE(B) do {                                                       \
    f32x4_t st[2][2];                                                         \
    _Pragma("unroll")                                                         \
    for (int ki_ = 0; ki_ < 2; ++ki_)                                         \
      _Pragma("unroll")                                                       \
      for (int qi_ = 0; qi_ < 2; ++qi_) st[ki_][qi_] = zero4;                 \
    __builtin_amdgcn_s_setprio(1);                                            \
    _Pragma("unroll")                                                         \
    for (int kc_ = 0; kc_ < 2; ++kc_)                                         \
      _Pragma("unroll")                                                       \
      for (int ki_ = 0; ki_ < 2; ++ki_)                                       \
        _Pragma("unroll")                                                     \
        for (int qi_ = 0; qi_ < 2; ++qi_)                                     \
          st[ki_][qi_] = __builtin_amdgcn_mfma_f32_16x16x32_bf16(             \
              kf[B][ki_][kc_].v, qf[qi_][kc_].v, st[ki_][qi_], 0, 0, 0);      \
    __builtin_amdgcn_s_setprio(0);                                            \
    _Pragma("unroll")                                                         \
    for (int ki_ = 0; ki_ < 2; ++ki_)                                         \
      _Pragma("unroll")                                                       \
      for (int qi_ = 0; qi_ < 2; ++qi_) {                                     \
        f32x4_t s_ = st[ki_][qi_];                                            \
        _Pragma("unroll")                                                     \
        for (int r_ = 0; r_ < 4; ++r_) {                                      \
          float p_ = __builtin_amdgcn_exp2f(s_[r_]);                          \
          s_[r_] = p_;                                                        \
          lsum[qi_] += p_;                                                    \
        }                                                                     \
        st[ki_][qi_] = s_;                                                    \
      }                                                                       \
    __builtin_amdgcn_s_setprio(1);                                            \
    _Pragma("unroll")                                                         \
    for (int qi_ = 0; qi_ < 2; ++qi_) {                                       \
      Frag pb_;                                                               \
      _Pragma("unroll")                                                       \
      for (int r_ = 0; r_ < 4; ++r_) {                                        \
        pb_.u[r_]     = f2bf(st[0][qi_][r_]);                                 \
        pb_.u[4 + r_] = f2bf(st[1][qi_][r_]);                                 \
      }                                                                       \
      _Pragma("unroll")                                                       \
      for (int di_ = 0; di_ < 4; ++di_)                                       \
        ot[di_][qi_] = __builtin_amdgcn_mfma_f32_16x16x32_bf16(               \
            vf[B][di_].v, pb_.v, ot[di_][qi_], 0, 0, 0);                      \
    }                                                                         \
    __builtin_amdgcn_s_setprio(0);                                            \
  } while (0)

  LOADF(0, 0, 0, 0);

  // ---- main loop: 4 chunks x 4 tiles of 32 keys; K streamed 1-chunk-ahead,
  //      fragments prefetched 1-tile-ahead ----
  #pragma unroll
  for (int c = 0; c < 4; ++c) {
    if (c < 3) issueK(c + 1);

    #pragma unroll
    for (int t4 = 0; t4 < 4; ++t4) {
      const int kt = c * 4 + t4;
      if (t4 == 0) { LOADF(1, c, 1, kt + 1); COMPUTE(0); }
      else if (t4 == 1) { LOADF(0, c, 2, kt + 1); COMPUTE(1); }
      else if (t4 == 2) { LOADF(1, c, 3, kt + 1); COMPUTE(0); }
      else { COMPUTE(1); }
    }

    if (c < 3) {
      writeK(c + 1);
      BARRIER_NODRAIN();
      LOADF(0, c + 1, 0, (c + 1) * 4);
    }
  }

  // ---- softmax denominators ----
  float rl[2];
  #pragma unroll
  for (int qi = 0; qi < 2; ++qi) {
    float s = lsum[qi];
    s += __shfl_xor(s, 16, 64);
    s += __shfl_xor(s, 32, 64);
    rl[qi] = 1.0f / s;
  }

  // ---- LePE conv from Vt LDS (lane = channel), wave rows wave*4..+3 ----
  float lout[32];
  {
    float wgt[9];
    const float* wp = lw + (size_t)(head * HDV + lane) * 9;
    #pragma unroll
    for (int i = 0; i < 9; ++i) wgt[i] = wp[i];
    const float bias = lb[head * HDV + lane];
    const int yb = wave * 4;
    const unsigned char* vrow = smem + VT_BASE + lane * 1048;

    float rm[8], rc[8], rp2[8];
    auto loadrow = [&](int y, float* dst) {
      if ((unsigned)y < 64u) {
        uint4 a = *(const uint4*)(vrow + y * 16);
        dst[0] = bf2f(a.x & 0xffffu); dst[1] = bf2f(a.x >> 16);
        dst[2] = bf2f(a.y & 0xffffu); dst[3] = bf2f(a.y >> 16);
        dst[4] = bf2f(a.z & 0xffffu); dst[5] = bf2f(a.z >> 16);
        dst[6] = bf2f(a.w & 0xffffu); dst[7] = bf2f(a.w >> 16);
      } else {
        #pragma unroll
        for (int x = 0; x < 8; ++x) dst[x] = 0.f;
      }
    };
    loadrow(yb - 1, rm);
    loadrow(yb, rc);
    #pragma unroll
    for (int yy = 0; yy < 4; ++yy) {
      loadrow(yb + yy + 1, rp2);
      #pragma unroll
      for (int x = 0; x < 8; ++x) {
        float acc = bias;
        if (x > 0) acc += rm[x-1]*wgt[0] + rc[x-1]*wgt[3] + rp2[x-1]*wgt[6];
        acc += rm[x]*wgt[1] + rc[x]*wgt[4] + rp2[x]*wgt[7];
        if (x < 7) acc += rm[x+1]*wgt[2] + rc[x+1]*wgt[5] + rp2[x+1]*wgt[8];
        lout[yy * 8 + x] = acc;
      }
      #pragma unroll
      for (int x = 0; x < 8; ++x) { rm[x] = rc[x]; rc[x] = rp2[x]; }
    }
  }

  BARRIER_NODRAIN();   // all PV + LePE reads of K/Vt done; LDS reusable

  unsigned char* bp = smem + wave * 4352;   // [32 tok][68 ch] bf16 per wave
  #pragma unroll
  for (int t = 0; t < 32; ++t)
    *(unsigned short*)(bp + t * 136 + 2 * lane) = f2bf(lout[t]);
  BARRIER_NODRAIN();

  // ---- normalize, add LePE, store ----
  #pragma unroll
  for (int qi = 0; qi < 2; ++qi) {
    const float rlq = rl[qi];
    const int tl = qi * 16 + l15;
    float* op = out + (size_t)grow(qbase + tl) * DIMV + head * HDV;
    #pragma unroll
    for (int di = 0; di < 4; ++di) {
      uint2 lv = *(const uint2*)(bp + tl * 136 + di * 32 + 8 * g);
      float4 o;
      o.x = ot[di][qi][0] * rlq + bf2f(lv.x & 0xffffu);
      o.y = ot[di][qi][1] * rlq + bf2f(lv.x >> 16);
      o.z = ot[di][qi][2] * rlq + bf2f(lv.y & 0xffffu);
      o.w = ot[di][qi][3] * rlq + bf2f(lv.y >> 16);
      *(float4*)(op + di * 16 + 4 * g) = o;
    }
  }
#undef LOADF
#undef COMPUTE
}

extern "C" void kernel_launch(void* const* d_in, const int* in_sizes, int n_in,
                              void* d_out, int out_size, void* d_ws, size_t ws_size,
                              hipStream_t stream) {
  const float* qkv = (const float*)d_in[0];
  const float* lw  = (const float*)d_in[1];
  const float* lb  = (const float*)d_in[2];
  float* out = (float*)d_out;
  (void)in_sizes; (void)n_in; (void)out_size; (void)d_ws; (void)ws_size;

  dim3 grid(512);    // 64 win x 8 heads
  dim3 block(1024);  // 16 waves x 32 queries
  hipLaunchKernelGGL(lepe_attn_kernel, grid, block, 0, stream, qkv, lw, lb, out);
}

// Round 13
// 76.358 us; speedup vs baseline: 1.1696x; 1.1690x over previous
//
#include <hip/hip_runtime.h>
#include <hip/hip_bf16.h>

#define DIMV 512
#define HDV  64
#define VSTR 524                          // shorts per Vt row: 1048 B
#define VT_BASE 65536                     // K region: 512 rows x 128 B (XOR-swizzled)
#define SMEM_B (VT_BASE + 64 * VSTR * 2)  // 132,608 B

typedef __bf16 bf16x8_t __attribute__((ext_vector_type(8)));
typedef float f32x4_t __attribute__((ext_vector_type(4)));

union Frag { bf16x8_t v; unsigned short u[8]; unsigned int w[4]; uint2 d[2]; uint4 q; };

static __device__ __forceinline__ unsigned short f2bf(float f) {
  return __builtin_bit_cast(unsigned short, (__bf16)f);
}
static __device__ __forceinline__ float bf2f(unsigned int h) {
  return __builtin_bit_cast(float, h << 16);
}

// LDS-visibility-only barrier: vmcnt NOT drained (carrier loads stay in flight).
#define BARRIER_NODRAIN() asm volatile("s_waitcnt lgkmcnt(0)\n\ts_barrier" ::: "memory")

__global__ __launch_bounds__(1024, 4)
void lepe_attn_kernel(const float* __restrict__ qkv,
                      const float* __restrict__ lw,
                      const float* __restrict__ lb,
                      float* __restrict__ out)
{
  __shared__ __align__(16) unsigned char smem[SMEM_B];

  // XCD co-location: consecutive blockIdx (-> round-robin across the 8 XCDs)
  // now walk WINDOWS; the 8 heads of one window sit at stride 64 and land on
  // the SAME XCD, sharing that window's 3 MB of qkv token rows in its L2.
  const int head = blockIdx.x >> 6;
  const int win  = blockIdx.x & 63;
  const int bat  = win >> 3;
  const int nw   = win & 7;

  const int tid  = threadIdx.x;
  const int wave = tid >> 6, lane = tid & 63;
  const int l15  = lane & 15, g = lane >> 4;

  const float* qptr = qkv;
  const float* kptr = qkv + 16777216;
  const float* vptr = qkv + 33554432;
  const int rowbase = bat * 4096;

  auto grow = [&](int tok) -> int {
    return rowbase + ((tok >> 3) << 6) + (nw << 3) + (tok & 7);
  };

  // ---- staging mapping: token s_t (0..63 within group), channel quad s_c ----
  const int s_t = tid >> 4;
  const int s_c = (tid & 15) * 4;
  const size_t GSTRIDE = 262144;            // floats between 64-token groups
  const float* kg = kptr + (size_t)grow(s_t) * DIMV + head * HDV + s_c;
  const float* vg = vptr + (size_t)grow(s_t) * DIMV + head * HDV + s_c;
  const int kwbase = s_t * 128 + ((s_c * 2) ^ ((s_t & 7) << 4));

  // chunk c = groups {2c, 2c+1} = keys/tokens 128c .. 128c+127
  float4 ck0, ck1, cv0, cv1;
  auto issueC = [&](int c) {
    ck0 = *(const float4*)(kg + (size_t)(2 * c) * GSTRIDE);
    ck1 = *(const float4*)(kg + (size_t)(2 * c + 1) * GSTRIDE);
    cv0 = *(const float4*)(vg + (size_t)(2 * c) * GSTRIDE);
    cv1 = *(const float4*)(vg + (size_t)(2 * c + 1) * GSTRIDE);
  };
  auto writeC = [&](int c) {
    uint2 kp;
    kp.x = (unsigned)f2bf(ck0.x) | ((unsigned)f2bf(ck0.y) << 16);
    kp.y = (unsigned)f2bf(ck0.z) | ((unsigned)f2bf(ck0.w) << 16);
    *(uint2*)(smem + (2 * c) * 8192 + kwbase) = kp;
    kp.x = (unsigned)f2bf(ck1.x) | ((unsigned)f2bf(ck1.y) << 16);
    kp.y = (unsigned)f2bf(ck1.z) | ((unsigned)f2bf(ck1.w) << 16);
    *(uint2*)(smem + (2 * c + 1) * 8192 + kwbase) = kp;
    unsigned short* vt = (unsigned short*)(smem + VT_BASE);
    #pragma unroll
    for (int gi = 0; gi < 2; ++gi) {
      const float4 vv = gi ? cv1 : cv0;
      const int t = (2 * c + gi) * 64 + s_t;
      float fv[4] = {vv.x, vv.y, vv.z, vv.w};
      #pragma unroll
      for (int i = 0; i < 4; ++i)
        vt[(s_c + i) * VSTR + t] = f2bf(fv[i]);
    }
  };

  // ---- prologue: chunk 0 + Q issued; convert; publish ----
  issueC(0);

  const float QSC = 0.1803368801f;          // 0.125 * log2(e): P = exp2(S)
  const int qbase = wave * 32;
  float4 qin[8];
  #pragma unroll
  for (int qi = 0; qi < 2; ++qi) {
    const float* qp = qptr + (size_t)grow(qbase + qi * 16 + l15) * DIMV + head * HDV;
    #pragma unroll
    for (int kc = 0; kc < 2; ++kc) {
      qin[qi * 4 + kc * 2 + 0] = *(const float4*)(qp + kc * 32 + 8 * g);
      qin[qi * 4 + kc * 2 + 1] = *(const float4*)(qp + kc * 32 + 8 * g + 4);
    }
  }

  writeC(0);

  Frag qf[2][2];
  #pragma unroll
  for (int qi = 0; qi < 2; ++qi)
    #pragma unroll
    for (int kc = 0; kc < 2; ++kc) {
      const float4 f0 = qin[qi * 4 + kc * 2 + 0];
      const float4 f1 = qin[qi * 4 + kc * 2 + 1];
      qf[qi][kc].u[0] = f2bf(f0.x * QSC); qf[qi][kc].u[1] = f2bf(f0.y * QSC);
      qf[qi][kc].u[2] = f2bf(f0.z * QSC); qf[qi][kc].u[3] = f2bf(f0.w * QSC);
      qf[qi][kc].u[4] = f2bf(f1.x * QSC); qf[qi][kc].u[5] = f2bf(f1.y * QSC);
      qf[qi][kc].u[6] = f2bf(f1.z * QSC); qf[qi][kc].u[7] = f2bf(f1.w * QSC);
    }

  __syncthreads();

  const f32x4_t zero4 = {0.f, 0.f, 0.f, 0.f};
  f32x4_t ot[4][2];
  #pragma unroll
  for (int di = 0; di < 4; ++di)
    #pragma unroll
    for (int qi = 0; qi < 2; ++qi) ot[di][qi] = zero4;
  float lsumA[2] = {0.f, 0.f};   // split accumulators: two 8-deep chains per tile
  float lsumB[2] = {0.f, 0.f};

  const int ksw = (l15 & 7) << 4;

  // ---- main loop: 4 chunks x 4 tiles of 32 keys; K+V streamed 1-ahead ----
  #pragma unroll
  for (int c = 0; c < 4; ++c) {
    if (c < 3) issueC(c + 1);

    #pragma unroll
    for (int t4 = 0; t4 < 4; ++t4) {
      const int kt = c * 4 + t4;

      Frag kf[2][2];
      #pragma unroll
      for (int ki = 0; ki < 2; ++ki) {
        const unsigned char* rowp = smem + (kt * 32 + ki * 16 + l15) * 128;
        #pragma unroll
        for (int kc = 0; kc < 2; ++kc)
          kf[ki][kc].q = *(const uint4*)(rowp + ((kc * 64 + g * 16) ^ ksw));
      }

      f32x4_t st[2][2];
      #pragma unroll
      for (int ki = 0; ki < 2; ++ki)
        #pragma unroll
        for (int qi = 0; qi < 2; ++qi) st[ki][qi] = zero4;

      #pragma unroll
      for (int kc = 0; kc < 2; ++kc)
        #pragma unroll
        for (int ki = 0; ki < 2; ++ki)
          #pragma unroll
          for (int qi = 0; qi < 2; ++qi)
            st[ki][qi] = __builtin_amdgcn_mfma_f32_16x16x32_bf16(
                kf[ki][kc].v, qf[qi][kc].v, st[ki][qi], 0, 0, 0);

      #pragma unroll
      for (int ki = 0; ki < 2; ++ki)
        #pragma unroll
        for (int qi = 0; qi < 2; ++qi) {
          f32x4_t s = st[ki][qi];
          #pragma unroll
          for (int r = 0; r < 4; ++r) {
            float pr = __builtin_amdgcn_exp2f(s[r]);
            s[r] = pr;
            if (ki == 0) lsumA[qi] += pr;
            else         lsumB[qi] += pr;
          }
          st[ki][qi] = s;
        }

      Frag vf[4];
      #pragma unroll
      for (int di = 0; di < 4; ++di) {
        const unsigned char* vp = smem + VT_BASE + (di * 16 + l15) * (VSTR * 2)
                                  + kt * 64 + 8 * g;
        vf[di].d[0] = *(const uint2*)(vp);
        vf[di].d[1] = *(const uint2*)(vp + 32);
      }

      #pragma unroll
      for (int qi = 0; qi < 2; ++qi) {
        Frag pb;
        #pragma unroll
        for (int r = 0; r < 4; ++r) {
          pb.u[r]     = f2bf(st[0][qi][r]);
          pb.u[4 + r] = f2bf(st[1][qi][r]);
        }
        #pragma unroll
        for (int di = 0; di < 4; ++di)
          ot[di][qi] = __builtin_amdgcn_mfma_f32_16x16x32_bf16(
              vf[di].v, pb.v, ot[di][qi], 0, 0, 0);
      }
    }

    if (c < 3) { writeC(c + 1); BARRIER_NODRAIN(); }
  }

  // ---- softmax denominators ----
  float rl[2];
  #pragma unroll
  for (int qi = 0; qi < 2; ++qi) {
    float s = lsumA[qi] + lsumB[qi];
    s += __shfl_xor(s, 16, 64);
    s += __shfl_xor(s, 32, 64);
    rl[qi] = 1.0f / s;
  }

  // ---- LePE conv from Vt LDS (lane = channel), wave rows wave*4..+3 ----
  float lout[32];
  {
    float wgt[9];
    const float* wp = lw + (size_t)(head * HDV + lane) * 9;
    #pragma unroll
    for (int i = 0; i < 9; ++i) wgt[i] = wp[i];
    const float bias = lb[head * HDV + lane];
    const int yb = wave * 4;
    const unsigned char* vrow = smem + VT_BASE + lane * (VSTR * 2);

    float rm[8], rc[8], rp2[8];
    auto loadrow = [&](int y, float* dst) {
      if ((unsigned)y < 64u) {
        const unsigned char* pp = vrow + y * 16;
        unsigned a0 = *(const unsigned*)(pp);
        unsigned a1 = *(const unsigned*)(pp + 4);
        unsigned a2 = *(const unsigned*)(pp + 8);
        unsigned a3 = *(const unsigned*)(pp + 12);
        dst[0] = bf2f(a0 & 0xffffu); dst[1] = bf2f(a0 >> 16);
        dst[2] = bf2f(a1 & 0xffffu); dst[3] = bf2f(a1 >> 16);
        dst[4] = bf2f(a2 & 0xffffu); dst[5] = bf2f(a2 >> 16);
        dst[6] = bf2f(a3 & 0xffffu); dst[7] = bf2f(a3 >> 16);
      } else {
        #pragma unroll
        for (int x = 0; x < 8; ++x) dst[x] = 0.f;
      }
    };
    loadrow(yb - 1, rm);
    loadrow(yb, rc);
    #pragma unroll
    for (int yy = 0; yy < 4; ++yy) {
      loadrow(yb + yy + 1, rp2);
      #pragma unroll
      for (int x = 0; x < 8; ++x) {
        float acc = bias;
        if (x > 0) acc += rm[x-1]*wgt[0] + rc[x-1]*wgt[3] + rp2[x-1]*wgt[6];
        acc += rm[x]*wgt[1] + rc[x]*wgt[4] + rp2[x]*wgt[7];
        if (x < 7) acc += rm[x+1]*wgt[2] + rc[x+1]*wgt[5] + rp2[x+1]*wgt[8];
        lout[yy * 8 + x] = acc;
      }
      #pragma unroll
      for (int x = 0; x < 8; ++x) { rm[x] = rc[x]; rc[x] = rp2[x]; }
    }
  }

  BARRIER_NODRAIN();   // all PV + LePE reads of Vt done; reuse LDS for bounce

  unsigned char* bp = smem + wave * 4352;   // [32 tok][68 ch] bf16 per wave
  #pragma unroll
  for (int t = 0; t < 32; ++t)
    *(unsigned short*)(bp + t * 136 + 2 * lane) = f2bf(lout[t]);
  BARRIER_NODRAIN();

  // ---- normalize, add LePE, store ----
  #pragma unroll
  for (int qi = 0; qi < 2; ++qi) {
    const float rlq = rl[qi];
    const int tl = qi * 16 + l15;
    float* op = out + (size_t)grow(qbase + tl) * DIMV + head * HDV;
    #pragma unroll
    for (int di = 0; di < 4; ++di) {
      uint2 lv = *(const uint2*)(bp + tl * 136 + di * 32 + 8 * g);
      float4 o;
      o.x = ot[di][qi][0] * rlq + bf2f(lv.x & 0xffffu);
      o.y = ot[di][qi][1] * rlq + bf2f(lv.x >> 16);
      o.z = ot[di][qi][2] * rlq + bf2f(lv.y & 0xffffu);
      o.w = ot[di][qi][3] * rlq + bf2f(lv.y >> 16);
      *(float4*)(op + di * 16 + 4 * g) = o;
    }
  }
}

extern "C" void kernel_launch(void* const* d_in, const int* in_sizes, int n_in,
                              void* d_out, int out_size, void* d_ws, size_t ws_size,
                              hipStream_t stream) {
  const float* qkv = (const float*)d_in[0];
  const float* lw  = (const float*)d_in[1];
  const float* lb  = (const float*)d_in[2];
  float* out = (float*)d_out;
  (void)in_sizes; (void)n_in; (void)out_size; (void)d_ws; (void)ws_size;

  dim3 grid(512);    // blockIdx = head*64 + win: heads of a window share an XCD
  dim3 block(1024);  // 16 waves x 32 queries
  hipLaunchKernelGGL(lepe_attn_kernel, grid, block, 0, stream, qkv, lw, lb, out);
}

// Round 14
// 75.064 us; speedup vs baseline: 1.1897x; 1.0172x over previous
//
#include <hip/hip_runtime.h>
#include <hip/hip_bf16.h>

#define DIMV 512
#define HDV  64
#define VBASE 65536                   // K: 16 tiles x 4096 B at 0; V: 16 tiles x 4096 B at VBASE
#define SMEM_B 131072

typedef __bf16 bf16x8_t __attribute__((ext_vector_type(8)));
typedef float f32x4_t __attribute__((ext_vector_type(4)));

union Frag { bf16x8_t v; unsigned short u[8]; unsigned int w[4]; uint2 d[2]; uint4 q; };

static __device__ __forceinline__ unsigned short f2bf(float f) {
  return __builtin_bit_cast(unsigned short, (__bf16)f);
}
static __device__ __forceinline__ float bf2f(unsigned int h) {
  return __builtin_bit_cast(float, h << 16);
}
static __device__ __forceinline__ uint2 pack4(const float4 f) {
  uint2 r;
  r.x = (unsigned)f2bf(f.x) | ((unsigned)f2bf(f.y) << 16);
  r.y = (unsigned)f2bf(f.z) | ((unsigned)f2bf(f.w) << 16);
  return r;
}

// LDS-visibility-only barrier: vmcnt NOT drained (carrier loads stay in flight).
#define BARRIER_NODRAIN() asm volatile("s_waitcnt lgkmcnt(0)\n\ts_barrier" ::: "memory")

__global__ __launch_bounds__(1024, 4)
void lepe_attn_kernel(const float* __restrict__ qkv,
                      const float* __restrict__ lw,
                      const float* __restrict__ lb,
                      float* __restrict__ out)
{
  __shared__ __align__(16) unsigned char smem[SMEM_B];

  const int head = blockIdx.x >> 6;   // R13 index split (measured best)
  const int win  = blockIdx.x & 63;
  const int bat  = win >> 3;
  const int nw   = win & 7;

  const int tid  = threadIdx.x;
  const int wave = tid >> 6, lane = tid & 63;
  const int l15  = lane & 15, g = lane >> 4;

  const float* qptr = qkv;
  const float* kptr = qkv + 16777216;
  const float* vptr = qkv + 33554432;
  const int rowbase = bat * 4096;

  auto grow = [&](int tok) -> int {
    return rowbase + ((tok >> 3) << 6) + (nw << 3) + (tok & 7);
  };

  // ---- staging mapping: token s_t (0..63 within group), channel quad s_c ----
  const int s_t = tid >> 4;
  const int s_c = (tid & 15) * 4;
  const size_t GSTRIDE = 262144;            // floats between 64-token groups
  const float* kg = kptr + (size_t)grow(s_t) * DIMV + head * HDV + s_c;
  const float* vg = vptr + (size_t)grow(s_t) * DIMV + head * HDV + s_c;

  // K fragment write (tile 4096 B = [ki2][kc2][1024B blk]); XOR swz bits 5-6.
  const int ki_w  = (s_t & 31) >> 4;
  const int l15k  = s_t & 15;
  const int kc_w  = s_c >> 5;
  const int gk_w  = (s_c & 31) >> 3;
  const int ksw_w = (((kc_w << 1) | (gk_w & 1)) << 5);
  const int kfoff = ki_w * 2048 + kc_w * 1024
                  + (((gk_w << 8) | (l15k << 4)) ^ ksw_w) + (s_c & 7) * 2;

  // V fragment write: element (d,t) -> tile=t>>5, byte = di*1024 +
  //   ((g*16+l15v)^di)<<4 + h*8 + r*2   (h=(t&31)>>4, g=(t&15)>>2, r=t&3)
  const int di_w = s_c >> 4;
  const int h_w  = (s_t & 31) >> 4;
  const int g_w  = (s_t & 15) >> 2;
  const int r_w  = s_t & 3;
  const int vtail = h_w * 8 + r_w * 2;

  // chunk c = groups {2c, 2c+1} = tokens/keys 128c .. 128c+127 (tiles 4c..4c+3)
  float4 ck0, ck1, cv0, cv1;
  auto issueC = [&](int c) {
    ck0 = *(const float4*)(kg + (size_t)(2 * c) * GSTRIDE);
    ck1 = *(const float4*)(kg + (size_t)(2 * c + 1) * GSTRIDE);
    cv0 = *(const float4*)(vg + (size_t)(2 * c) * GSTRIDE);
    cv1 = *(const float4*)(vg + (size_t)(2 * c + 1) * GSTRIDE);
  };
  auto writeC = [&](int c) {
    #pragma unroll
    for (int gi = 0; gi < 2; ++gi) {
      const int tile = 4 * c + 2 * gi + (s_t >> 5);
      *(uint2*)(smem + tile * 4096 + kfoff) = pack4(gi ? ck1 : ck0);
      const float4 vv = gi ? cv1 : cv0;
      float fv[4] = {vv.x, vv.y, vv.z, vv.w};
      unsigned char* vb = smem + VBASE + tile * 4096 + di_w * 1024 + vtail;
      #pragma unroll
      for (int i = 0; i < 4; ++i) {
        const int l15v = (s_c & 15) + i;
        *(unsigned short*)(vb + ((((g_w << 4) + l15v) ^ di_w) << 4)) = f2bf(fv[i]);
      }
    }
  };

  // ---- prologue: chunk 0 + Q issued; convert; publish ----
  issueC(0);

  const float QSC = 0.1803368801f;          // 0.125 * log2(e): P = exp2(S)
  const int qbase = wave * 32;
  float4 qin[8];
  #pragma unroll
  for (int qi = 0; qi < 2; ++qi) {
    const float* qp = qptr + (size_t)grow(qbase + qi * 16 + l15) * DIMV + head * HDV;
    #pragma unroll
    for (int kc = 0; kc < 2; ++kc) {
      qin[qi * 4 + kc * 2 + 0] = *(const float4*)(qp + kc * 32 + 8 * g);
      qin[qi * 4 + kc * 2 + 1] = *(const float4*)(qp + kc * 32 + 8 * g + 4);
    }
  }

  writeC(0);

  Frag qf[2][2];
  #pragma unroll
  for (int qi = 0; qi < 2; ++qi)
    #pragma unroll
    for (int kc = 0; kc < 2; ++kc) {
      const float4 f0 = qin[qi * 4 + kc * 2 + 0];
      const float4 f1 = qin[qi * 4 + kc * 2 + 1];
      qf[qi][kc].u[0] = f2bf(f0.x * QSC); qf[qi][kc].u[1] = f2bf(f0.y * QSC);
      qf[qi][kc].u[2] = f2bf(f0.z * QSC); qf[qi][kc].u[3] = f2bf(f0.w * QSC);
      qf[qi][kc].u[4] = f2bf(f1.x * QSC); qf[qi][kc].u[5] = f2bf(f1.y * QSC);
      qf[qi][kc].u[6] = f2bf(f1.z * QSC); qf[qi][kc].u[7] = f2bf(f1.w * QSC);
    }

  __syncthreads();

  const f32x4_t zero4 = {0.f, 0.f, 0.f, 0.f};
  f32x4_t ot[4][2];
  #pragma unroll
  for (int di = 0; di < 4; ++di)
    #pragma unroll
    for (int qi = 0; qi < 2; ++qi) ot[di][qi] = zero4;
  float lsumA[2] = {0.f, 0.f};
  float lsumB[2] = {0.f, 0.f};

  // per-lane read swizzles
  const int ksr0 = ((g & 1) << 5);          // kc=0: ((0<<1)|(g&1))<<5
  const int ksr1 = ksr0 | 64;               // kc=1
  const int kread0 = ((lane << 4) ^ ksr0);
  const int kread1 = 1024 + ((lane << 4) ^ ksr1);

  // ---- main loop: 4 chunks x 4 tiles of 32 keys; K+V streamed 1-ahead ----
  #pragma unroll
  for (int c = 0; c < 4; ++c) {
    if (c < 3) issueC(c + 1);

    #pragma unroll
    for (int t4 = 0; t4 < 4; ++t4) {
      const int kt = c * 4 + t4;
      const unsigned char* kb = smem + kt * 4096;

      Frag kf[2][2];
      #pragma unroll
      for (int ki = 0; ki < 2; ++ki) {
        kf[ki][0].q = *(const uint4*)(kb + ki * 2048 + kread0);
        kf[ki][1].q = *(const uint4*)(kb + ki * 2048 + kread1);
      }

      f32x4_t st[2][2];
      #pragma unroll
      for (int ki = 0; ki < 2; ++ki)
        #pragma unroll
        for (int qi = 0; qi < 2; ++qi) st[ki][qi] = zero4;

      #pragma unroll
      for (int kc = 0; kc < 2; ++kc)
        #pragma unroll
        for (int ki = 0; ki < 2; ++ki)
          #pragma unroll
          for (int qi = 0; qi < 2; ++qi)
            st[ki][qi] = __builtin_amdgcn_mfma_f32_16x16x32_bf16(
                kf[ki][kc].v, qf[qi][kc].v, st[ki][qi], 0, 0, 0);

      #pragma unroll
      for (int ki = 0; ki < 2; ++ki)
        #pragma unroll
        for (int qi = 0; qi < 2; ++qi) {
          f32x4_t s = st[ki][qi];
          #pragma unroll
          for (int r = 0; r < 4; ++r) {
            float pr = __builtin_amdgcn_exp2f(s[r]);
            s[r] = pr;
            if (ki == 0) lsumA[qi] += pr;
            else         lsumB[qi] += pr;
          }
          st[ki][qi] = s;
        }

      Frag vf[4];
      #pragma unroll
      for (int di = 0; di < 4; ++di)
        vf[di].q = *(const uint4*)(smem + VBASE + kt * 4096 + di * 1024
                                   + ((lane ^ di) << 4));

      #pragma unroll
      for (int qi = 0; qi < 2; ++qi) {
        Frag pb;
        #pragma unroll
        for (int r = 0; r < 4; ++r) {
          pb.u[r]     = f2bf(st[0][qi][r]);
          pb.u[4 + r] = f2bf(st[1][qi][r]);
        }
        #pragma unroll
        for (int di = 0; di < 4; ++di)
          ot[di][qi] = __builtin_amdgcn_mfma_f32_16x16x32_bf16(
              vf[di].v, pb.v, ot[di][qi], 0, 0, 0);
      }
    }

    if (c < 3) { writeC(c + 1); BARRIER_NODRAIN(); }
  }

  // ---- softmax denominators ----
  float rl[2];
  #pragma unroll
  for (int qi = 0; qi < 2; ++qi) {
    float s = lsumA[qi] + lsumB[qi];
    s += __shfl_xor(s, 16, 64);
    s += __shfl_xor(s, 32, 64);
    rl[qi] = 1.0f / s;
  }

  // ---- LePE conv from V-frag LDS (lane = channel), wave rows wave*4..+3 ----
  float lout[32];
  {
    float wgt[9];
    const float* wp = lw + (size_t)(head * HDV + lane) * 9;
    #pragma unroll
    for (int i = 0; i < 9; ++i) wgt[i] = wp[i];
    const float bias = lb[head * HDV + lane];
    const int yb = wave * 4;
    const int dil = lane >> 4;
    const unsigned char* vrow = smem + VBASE + dil * 1024;

    float rm[8], rc[8], rp2[8];
    auto loadrow = [&](int y, float* dst) {
      if ((unsigned)y < 64u) {
        const int tile = y >> 2;
        const int hh = (y & 3) >> 1;
        const int gb = (y & 1) * 2;
        const unsigned char* pbase = vrow + tile * 4096 + hh * 8;
        uint2 a = *(const uint2*)(pbase + ((((gb << 4) + l15) ^ dil) << 4));
        uint2 b = *(const uint2*)(pbase + (((((gb + 1) << 4) + l15) ^ dil) << 4));
        dst[0] = bf2f(a.x & 0xffffu); dst[1] = bf2f(a.x >> 16);
        dst[2] = bf2f(a.y & 0xffffu); dst[3] = bf2f(a.y >> 16);
        dst[4] = bf2f(b.x & 0xffffu); dst[5] = bf2f(b.x >> 16);
        dst[6] = bf2f(b.y & 0xffffu); dst[7] = bf2f(b.y >> 16);
      } else {
        #pragma unroll
        for (int x = 0; x < 8; ++x) dst[x] = 0.f;
      }
    };
    loadrow(yb - 1, rm);
    loadrow(yb, rc);
    #pragma unroll
    for (int yy = 0; yy < 4; ++yy) {
      loadrow(yb + yy + 1, rp2);
      #pragma unroll
      for (int x = 0; x < 8; ++x) {
        float acc = bias;
        if (x > 0) acc += rm[x-1]*wgt[0] + rc[x-1]*wgt[3] + rp2[x-1]*wgt[6];
        acc += rm[x]*wgt[1] + rc[x]*wgt[4] + rp2[x]*wgt[7];
        if (x < 7) acc += rm[x+1]*wgt[2] + rc[x+1]*wgt[5] + rp2[x+1]*wgt[8];
        lout[yy * 8 + x] = acc;
      }
      #pragma unroll
      for (int x = 0; x < 8; ++x) { rm[x] = rc[x]; rc[x] = rp2[x]; }
    }
  }

  BARRIER_NODRAIN();   // all PV + LePE reads done; reuse LDS for bounce

  unsigned char* bp = smem + wave * 4352;   // [32 tok][68 ch] bf16 per wave
  #pragma unroll
  for (int t = 0; t < 32; ++t)
    *(unsigned short*)(bp + t * 136 + 2 * lane) = f2bf(lout[t]);
  BARRIER_NODRAIN();

  // ---- normalize, add LePE, store ----
  #pragma unroll
  for (int qi = 0; qi < 2; ++qi) {
    const float rlq = rl[qi];
    const int tl = qi * 16 + l15;
    float* op = out + (size_t)grow(qbase + tl) * DIMV + head * HDV;
    #pragma unroll
    for (int di = 0; di < 4; ++di) {
      uint2 lv = *(const uint2*)(bp + tl * 136 + di * 32 + 8 * g);
      float4 o;
      o.x = ot[di][qi][0] * rlq + bf2f(lv.x & 0xffffu);
      o.y = ot[di][qi][1] * rlq + bf2f(lv.x >> 16);
      o.z = ot[di][qi][2] * rlq + bf2f(lv.y & 0xffffu);
      o.w = ot[di][qi][3] * rlq + bf2f(lv.y >> 16);
      *(float4*)(op + di * 16 + 4 * g) = o;
    }
  }
}

extern "C" void kernel_launch(void* const* d_in, const int* in_sizes, int n_in,
                              void* d_out, int out_size, void* d_ws, size_t ws_size,
                              hipStream_t stream) {
  const float* qkv = (const float*)d_in[0];
  const float* lw  = (const float*)d_in[1];
  const float* lb  = (const float*)d_in[2];
  float* out = (float*)d_out;
  (void)in_sizes; (void)n_in; (void)out_size; (void)d_ws; (void)ws_size;

  dim3 grid(512);    // blockIdx = head*64 + win
  dim3 block(1024);  // 16 waves x 32 queries
  hipLaunchKernelGGL(lepe_attn_kernel, grid, block, 0, stream, qkv, lw, lb, out);
}